// Round 6
// baseline (212.011 us; speedup 1.0000x reference)
//
#include <hip/hip_runtime.h>
#include <cstdint>

// Problem constants (fixed by the reference: B=64,S=512,IN=OUT=256,R=40,NB=3,E=262144)
#define N_NODES 32768
#define IN_F    256
#define OUT_F   256
#define NBASES  3
#define N_EDGES 262144
#define K_DIM   (NBASES * IN_F)    // 768: GEMM reduction dim (b*256 + i)
#define ZROWS   32                 // nodes per fused block

typedef __attribute__((ext_vector_type(8))) short bf16x8;
typedef __attribute__((ext_vector_type(4))) float f32x4;

__device__ __forceinline__ unsigned short f2bf(float x) {
    union { float f; unsigned int u; } c; c.f = x;
    unsigned int u = c.u;
    u = (u + 0x7FFFu + ((u >> 16) & 1u)) >> 16;   // round-to-nearest-even
    return (unsigned short)u;
}
__device__ __forceinline__ float bf2f(unsigned short h) {
    union { unsigned int u; float f; } c; c.u = ((unsigned int)h) << 16;
    return c.f;
}

__device__ __forceinline__ void async_copy16(const void* g, void* l) {
    __builtin_amdgcn_global_load_lds(
        (const __attribute__((address_space(1))) unsigned int*)g,
        (__attribute__((address_space(3))) unsigned int*)l, 16, 0, 0);
}

// ---------------------------------------------------------------------------
// Prep (fused): blocks [0,8192) convert text f32 -> hb bf16; blocks
// [8192,8384) transpose bases -> Wt bf16; blocks [8384,8512) zero counts.
// ---------------------------------------------------------------------------
__global__ __launch_bounds__(256) void prep_kernel(
    const float* __restrict__ text,     // [N_NODES, 256] f32
    const float* __restrict__ bases,    // [768, 256] f32
    unsigned short* __restrict__ hb,    // [N_NODES, 256] bf16
    unsigned short* __restrict__ Wt,    // [256, 768] bf16
    int* __restrict__ counts)           // [N_NODES] -> zeroed
{
    const int tid = threadIdx.x;
    if (blockIdx.x < 8192) {
        int i = blockIdx.x * 256 + tid;            // float4 index
        float4 v = reinterpret_cast<const float4*>(text)[i];
        ushort4 o;
        o.x = f2bf(v.x); o.y = f2bf(v.y); o.z = f2bf(v.z); o.w = f2bf(v.w);
        reinterpret_cast<ushort4*>(hb)[i] = o;
    } else if (blockIdx.x < 8384) {
        int tb = blockIdx.x - 8192;                // [0,192)
        int kb = tb % 24, ob = tb / 24;            // 32-wide tiles
        __shared__ float tile[32][33];
        int c = tid & 31, r8 = tid >> 5;
        #pragma unroll
        for (int i = 0; i < 4; ++i) {
            int r = r8 + 8 * i;
            tile[r][c] = bases[(size_t)(kb * 32 + r) * OUT_F + ob * 32 + c];
        }
        __syncthreads();
        #pragma unroll
        for (int i = 0; i < 4; ++i) {
            int r = r8 + 8 * i;                    // output row within o-tile
            Wt[(size_t)(ob * 32 + r) * K_DIM + kb * 32 + c] = f2bf(tile[c][r]);
        }
    } else {
        int i = (blockIdx.x - 8384) * 256 + tid;   // [0, 32768)
        counts[i] = 0;
    }
}

// ---------------------------------------------------------------------------
// Counting sort of edges by dst: histogram -> scan -> scatter(packed int2)
// ---------------------------------------------------------------------------
__global__ __launch_bounds__(256) void hist_kernel(
    const int* __restrict__ dst, int* __restrict__ counts)
{
    int e4 = blockIdx.x * 256 + threadIdx.x;
    int4 d = reinterpret_cast<const int4*>(dst)[e4];
    atomicAdd(&counts[d.x], 1);
    atomicAdd(&counts[d.y], 1);
    atomicAdd(&counts[d.z], 1);
    atomicAdd(&counts[d.w], 1);
}

// Single block, 1024 threads, 32 counters each. Converts counts -> cursor
// in place and writes the exclusive-scan offsets.
__global__ __launch_bounds__(1024) void scan_kernel(
    int* __restrict__ counts,        // in: histogram; out: cursor (in place)
    int* __restrict__ offsets)       // [N_NODES+1]
{
    __shared__ int wsum[16];
    const int tid = threadIdx.x;
    const int wave = tid >> 6, lane = tid & 63;
    const int base = tid * 32;
    int local[32];
    int sum = 0;
    #pragma unroll
    for (int k8 = 0; k8 < 8; ++k8) {
        int4 v = reinterpret_cast<const int4*>(counts + base)[k8];
        local[k8 * 4 + 0] = v.x; local[k8 * 4 + 1] = v.y;
        local[k8 * 4 + 2] = v.z; local[k8 * 4 + 3] = v.w;
        sum += v.x + v.y + v.z + v.w;
    }
    int inc = sum;                            // wave-inclusive scan of sums
    #pragma unroll
    for (int off = 1; off < 64; off <<= 1) {
        int v = __shfl_up(inc, off);
        if (lane >= off) inc += v;
    }
    if (lane == 63) wsum[wave] = inc;
    __syncthreads();
    if (wave == 0 && lane < 16) {             // scan the 16 wave totals
        int v = wsum[lane];
        #pragma unroll
        for (int off = 1; off < 16; off <<= 1) {
            int u = __shfl_up(v, off);
            if (lane >= off) v += u;
        }
        wsum[lane] = v;
    }
    __syncthreads();
    int run = inc - sum + (wave ? wsum[wave - 1] : 0);   // exclusive prefix
    #pragma unroll
    for (int k = 0; k < 32; ++k) {
        offsets[base + k] = run;
        counts[base + k] = run;               // cursor
        run += local[k];
    }
    if (tid == 1023) offsets[N_NODES] = run;  // == N_EDGES
}

// Packs per-edge (src, bf16(comp[rel,0..2])) so the fused kernel needs no
// comp lookups and invalid lanes (coef=0) are harmless.
__global__ __launch_bounds__(256) void scatter_kernel(
    const int* __restrict__ dst, const int* __restrict__ src,
    const int* __restrict__ rel, const float* __restrict__ comp,
    int* __restrict__ cursor, int2* __restrict__ packed2)
{
    int e4 = blockIdx.x * 256 + threadIdx.x;
    int4 d = reinterpret_cast<const int4*>(dst)[e4];
    int4 s = reinterpret_cast<const int4*>(src)[e4];
    int4 r = reinterpret_cast<const int4*>(rel)[e4];
    int dd[4] = { d.x, d.y, d.z, d.w };
    int ss[4] = { s.x, s.y, s.z, s.w };
    int rr[4] = { r.x, r.y, r.z, r.w };
    #pragma unroll
    for (int q = 0; q < 4; ++q) {
        float c0 = comp[rr[q] * 3 + 0];
        float c1 = comp[rr[q] * 3 + 1];
        float c2 = comp[rr[q] * 3 + 2];
        int w0 = ss[q] | ((int)f2bf(c0) << 16);
        int w1 = (int)f2bf(c1) | ((int)f2bf(c2) << 16);
        int pos = atomicAdd(&cursor[dd[q]], 1);
        packed2[pos] = make_int2(w0, w1);
    }
}

// ---------------------------------------------------------------------------
// FUSED aggregation + GEMM. Block = 32 dst nodes, 256 threads (4 waves).
// Phase 1: each wave aggregates 8 nodes; z-tile [32 x 768] lives ONLY in LDS
//   (48 KB), stored swizzled: slot(row, oct) = row*96 + (oct ^ (row & 7)),
//   16 B slots -> 2-way max bank aliasing on reads and ~4-way on the rare
//   writes (3 per node).
// Phase 2: K-loop (24 x BK=32): Wt slab 256x32 (16 KB) staged via
//   global_load_lds, A-frags read directly from the persistent z-tile.
//   Out tile 32x256, fused bias+ReLU. LDS 64 KB -> 2 blocks/CU.
// ---------------------------------------------------------------------------
__global__ __launch_bounds__(256, 2) void fused_kernel(
    const unsigned short* __restrict__ hb,    // [N_NODES, 256] bf16
    const int2* __restrict__ packed2,         // sorted by dst
    const int* __restrict__ offsets,          // [N_NODES+1]
    const unsigned short* __restrict__ Wt,    // [256, 768] bf16
    const float* __restrict__ bias,           // [256]
    float* __restrict__ out)                  // [N_NODES, 256] f32
{
    __shared__ __align__(16) unsigned short Zs[ZROWS * 96 * 8];   // 48 KB
    __shared__ __align__(16) unsigned short Bs[256 * 4 * 8];      // 16 KB

    const int tid  = threadIdx.x;
    const int wave = tid >> 6, lane = tid & 63;
    const int quad = lane >> 4, l16 = lane & 15;
    const int m0 = blockIdx.x * ZROWS;

    // ---------------- Phase 1: aggregate 8 nodes per wave ----------------
    for (int i = 0; i < 8; ++i) {
        const int m = wave * 8 + i;               // local z row
        const int node = m0 + m;
        const int start = offsets[node];
        const int end   = offsets[node + 1];

        float a[12] = {};
        for (int cb = start; cb < end; cb += 64) {
            int idx = cb + lane;
            int wx = 0, wy = 0;
            if (idx < end) { int2 w = packed2[idx]; wx = w.x; wy = w.y; }
            int cnt = min(64, end - cb);
            for (int j = 0; j < cnt; j += 4) {
                float c0[4], c1[4], c2[4];
                ushort4 u[4];
                #pragma unroll
                for (int q = 0; q < 4; ++q) {     // lanes >= cnt carry 0 coefs
                    int p0 = __shfl(wx, j + q);
                    int p1 = __shfl(wy, j + q);
                    int s = p0 & 0xFFFF;
                    c0[q] = bf2f((unsigned short)((unsigned)p0 >> 16));
                    c1[q] = bf2f((unsigned short)(p1 & 0xFFFF));
                    c2[q] = bf2f((unsigned short)((unsigned)p1 >> 16));
                    u[q] = *reinterpret_cast<const ushort4*>(
                        hb + (size_t)s * IN_F + lane * 4);
                }
                #pragma unroll
                for (int q = 0; q < 4; ++q) {
                    float v[4] = { bf2f(u[q].x), bf2f(u[q].y),
                                   bf2f(u[q].z), bf2f(u[q].w) };
                    #pragma unroll
                    for (int k = 0; k < 4; ++k) {
                        a[k]     += c0[q] * v[k];
                        a[4 + k] += c1[q] * v[k];
                        a[8 + k] += c2[q] * v[k];
                    }
                }
            }
        }

        // Dump 12 accumulators as bf16 into the swizzled z-tile.
        // Lane owns features seg*256 + lane*4 .. +4 -> oct = seg*32 + lane/2,
        // half-slot = lane&1.
        #pragma unroll
        for (int seg = 0; seg < 3; ++seg) {
            int oct  = seg * 32 + (lane >> 1);
            int phys = oct ^ (m & 7);
            ushort4 o;
            o.x = f2bf(a[seg * 4 + 0]); o.y = f2bf(a[seg * 4 + 1]);
            o.z = f2bf(a[seg * 4 + 2]); o.w = f2bf(a[seg * 4 + 3]);
            *reinterpret_cast<ushort4*>(
                &Zs[(m * 96 + phys) * 8 + (lane & 1) * 4]) = o;
        }
    }
    __syncthreads();   // z-tile complete

    // ---------------- Phase 2: out[32,256] = relu(z @ Wt^T + bias) --------
    // B staging map: slot p -> col = p>>2, phys = p&3, logical = phys^((col>>1)&3)
    const unsigned short* gB[4];
    int lB[4];
    #pragma unroll
    for (int c = 0; c < 4; ++c) {
        int p = c * 256 + wave * 64 + lane;
        int col = p >> 2;
        int logical = (p & 3) ^ ((col >> 1) & 3);
        gB[c] = Wt + (size_t)col * K_DIM + logical * 8;
        lB[c] = (c * 256 + wave * 64) * 8;        // wave-uniform base (elems)
    }

    f32x4 acc[2][4] = {};
    for (int s = 0; s < 24; ++s) {
        __syncthreads();   // all waves done reading Bs (prev step)
        #pragma unroll
        for (int c = 0; c < 4; ++c)
            async_copy16(gB[c] + s * 32, &Bs[lB[c]]);
        __syncthreads();   // copies drained (vmcnt(0) before barrier)

        bf16x8 af[2], bfr[4];
        #pragma unroll
        for (int i = 0; i < 2; ++i) {
            int m = i * 16 + l16;
            int phys = (s * 4 + quad) ^ (m & 7);
            af[i] = *reinterpret_cast<const bf16x8*>(&Zs[(m * 96 + phys) * 8]);
        }
        #pragma unroll
        for (int j = 0; j < 4; ++j) {
            int col = wave * 64 + j * 16 + l16;
            int physo = quad ^ ((col >> 1) & 3);
            bfr[j] = *reinterpret_cast<const bf16x8*>(&Bs[(col * 4 + physo) * 8]);
        }
        #pragma unroll
        for (int i = 0; i < 2; ++i)
            #pragma unroll
            for (int j = 0; j < 4; ++j)
                acc[i][j] = __builtin_amdgcn_mfma_f32_16x16x32_bf16(
                    af[i], bfr[j], acc[i][j], 0, 0, 0);
    }

    // Epilogue: C/D layout col = l16, row = quad*4 + r. Fused bias + ReLU.
    #pragma unroll
    for (int j = 0; j < 4; ++j) {
        int col = wave * 64 + j * 16 + l16;
        float bv = bias[col];
        #pragma unroll
        for (int i = 0; i < 2; ++i) {
            int row_base = m0 + i * 16 + quad * 4;
            #pragma unroll
            for (int r = 0; r < 4; ++r)
                out[(size_t)(row_base + r) * OUT_F + col] =
                    fmaxf(acc[i][j][r] + bv, 0.f);
        }
    }
}

extern "C" void kernel_launch(void* const* d_in, const int* in_sizes, int n_in,
                              void* d_out, int out_size, void* d_ws, size_t ws_size,
                              hipStream_t stream) {
    const float* text  = (const float*)d_in[0];   // [64,512,256] f32
    const int*   src   = (const int*)d_in[1];     // [E]
    const int*   dst   = (const int*)d_in[2];     // [E]
    const int*   rel   = (const int*)d_in[3];     // [E]
    const float* bases = (const float*)d_in[4];   // [3,256,256] f32 = [768,256]
    const float* comp  = (const float*)d_in[5];   // [40,3] f32
    const float* bias  = (const float*)d_in[6];   // [256] f32
    float* out = (float*)d_out;

    // Workspace layout (~19.5 MB; all chunks 16B-aligned):
    //   hb      : N*256*2   = 16,777,216 B
    //   packed2 : E*8       =  2,097,152 B
    //   offsets : (N+4)*4   =    131,088 B
    //   counts  : N*4       =    131,072 B
    //   Wt      : 256*768*2 =    393,216 B
    char* p = (char*)d_ws;
    unsigned short* hb = (unsigned short*)p;      p += (size_t)N_NODES * IN_F * 2;
    int2* packed2 = (int2*)p;                     p += (size_t)N_EDGES * 8;
    int* offsets  = (int*)p;                      p += (size_t)(N_NODES + 4) * 4;
    int* counts   = (int*)p;                      p += (size_t)N_NODES * 4;
    unsigned short* Wt = (unsigned short*)p;

    prep_kernel<<<8512, 256, 0, stream>>>(text, bases, hb, Wt, counts);
    hist_kernel<<<N_EDGES / 1024, 256, 0, stream>>>(dst, counts);
    scan_kernel<<<1, 1024, 0, stream>>>(counts, offsets);
    scatter_kernel<<<N_EDGES / 1024, 256, 0, stream>>>(
        dst, src, rel, comp, counts, packed2);
    fused_kernel<<<N_NODES / ZROWS, 256, 0, stream>>>(
        hb, packed2, offsets, Wt, bias, out);
}

// Round 7
// 203.874 us; speedup vs baseline: 1.0399x; 1.0399x over previous
//
#include <hip/hip_runtime.h>
#include <cstdint>

// Problem constants (fixed by the reference: B=64,S=512,IN=OUT=256,R=40,NB=3,E=262144)
#define N_NODES 32768
#define IN_F    256
#define OUT_F   256
#define NBASES  3
#define N_EDGES 262144
#define K_DIM   (NBASES * IN_F)    // 768: GEMM reduction dim (b*256 + i)
#define ZROWS   32                 // nodes per fused block

typedef __attribute__((ext_vector_type(8))) short bf16x8;
typedef __attribute__((ext_vector_type(4))) float f32x4;

__device__ __forceinline__ unsigned short f2bf(float x) {
    union { float f; unsigned int u; } c; c.f = x;
    unsigned int u = c.u;
    u = (u + 0x7FFFu + ((u >> 16) & 1u)) >> 16;   // round-to-nearest-even
    return (unsigned short)u;
}
__device__ __forceinline__ float bf2f(unsigned short h) {
    union { unsigned int u; float f; } c; c.u = ((unsigned int)h) << 16;
    return c.f;
}

__device__ __forceinline__ void async_copy16(const void* g, void* l) {
    __builtin_amdgcn_global_load_lds(
        (const __attribute__((address_space(1))) unsigned int*)g,
        (__attribute__((address_space(3))) unsigned int*)l, 16, 0, 0);
}

// ---------------------------------------------------------------------------
// Prep (fused): blocks [0,8192) convert text f32 -> hb bf16; blocks
// [8192,8384) transpose bases -> Wt bf16; blocks [8384,8512) zero counts.
// ---------------------------------------------------------------------------
__global__ __launch_bounds__(256) void prep_kernel(
    const float* __restrict__ text,     // [N_NODES, 256] f32
    const float* __restrict__ bases,    // [768, 256] f32
    unsigned short* __restrict__ hb,    // [N_NODES, 256] bf16
    unsigned short* __restrict__ Wt,    // [256, 768] bf16
    int* __restrict__ counts)           // [N_NODES] -> zeroed
{
    const int tid = threadIdx.x;
    if (blockIdx.x < 8192) {
        int i = blockIdx.x * 256 + tid;            // float4 index
        float4 v = reinterpret_cast<const float4*>(text)[i];
        ushort4 o;
        o.x = f2bf(v.x); o.y = f2bf(v.y); o.z = f2bf(v.z); o.w = f2bf(v.w);
        reinterpret_cast<ushort4*>(hb)[i] = o;
    } else if (blockIdx.x < 8384) {
        int tb = blockIdx.x - 8192;                // [0,192)
        int kb = tb % 24, ob = tb / 24;            // 32-wide tiles
        __shared__ float tile[32][33];
        int c = tid & 31, r8 = tid >> 5;
        #pragma unroll
        for (int i = 0; i < 4; ++i) {
            int r = r8 + 8 * i;
            tile[r][c] = bases[(size_t)(kb * 32 + r) * OUT_F + ob * 32 + c];
        }
        __syncthreads();
        #pragma unroll
        for (int i = 0; i < 4; ++i) {
            int r = r8 + 8 * i;                    // output row within o-tile
            Wt[(size_t)(ob * 32 + r) * K_DIM + kb * 32 + c] = f2bf(tile[c][r]);
        }
    } else {
        int i = (blockIdx.x - 8384) * 256 + tid;   // [0, 32768)
        counts[i] = 0;
    }
}

// ---------------------------------------------------------------------------
// Counting sort of edges by dst: histogram -> scan -> scatter(packed int2)
// ---------------------------------------------------------------------------
__global__ __launch_bounds__(256) void hist_kernel(
    const int* __restrict__ dst, int* __restrict__ counts)
{
    int e4 = blockIdx.x * 256 + threadIdx.x;
    int4 d = reinterpret_cast<const int4*>(dst)[e4];
    atomicAdd(&counts[d.x], 1);
    atomicAdd(&counts[d.y], 1);
    atomicAdd(&counts[d.z], 1);
    atomicAdd(&counts[d.w], 1);
}

// Single block, 1024 threads, 32 counters each. Converts counts -> cursor
// in place and writes the exclusive-scan offsets.
__global__ __launch_bounds__(1024) void scan_kernel(
    int* __restrict__ counts,        // in: histogram; out: cursor (in place)
    int* __restrict__ offsets)       // [N_NODES+1]
{
    __shared__ int wsum[16];
    const int tid = threadIdx.x;
    const int wave = tid >> 6, lane = tid & 63;
    const int base = tid * 32;
    int local[32];
    int sum = 0;
    #pragma unroll
    for (int k8 = 0; k8 < 8; ++k8) {
        int4 v = reinterpret_cast<const int4*>(counts + base)[k8];
        local[k8 * 4 + 0] = v.x; local[k8 * 4 + 1] = v.y;
        local[k8 * 4 + 2] = v.z; local[k8 * 4 + 3] = v.w;
        sum += v.x + v.y + v.z + v.w;
    }
    int inc = sum;                            // wave-inclusive scan of sums
    #pragma unroll
    for (int off = 1; off < 64; off <<= 1) {
        int v = __shfl_up(inc, off);
        if (lane >= off) inc += v;
    }
    if (lane == 63) wsum[wave] = inc;
    __syncthreads();
    if (wave == 0 && lane < 16) {             // scan the 16 wave totals
        int v = wsum[lane];
        #pragma unroll
        for (int off = 1; off < 16; off <<= 1) {
            int u = __shfl_up(v, off);
            if (lane >= off) v += u;
        }
        wsum[lane] = v;
    }
    __syncthreads();
    int run = inc - sum + (wave ? wsum[wave - 1] : 0);   // exclusive prefix
    #pragma unroll
    for (int k = 0; k < 32; ++k) {
        offsets[base + k] = run;
        counts[base + k] = run;               // cursor
        run += local[k];
    }
    if (tid == 1023) offsets[N_NODES] = run;  // == N_EDGES
}

// Packs per-edge (src, bf16(comp[rel,0..2])) so the fused kernel needs no
// comp lookups and invalid lanes (coef=0) are harmless.
__global__ __launch_bounds__(256) void scatter_kernel(
    const int* __restrict__ dst, const int* __restrict__ src,
    const int* __restrict__ rel, const float* __restrict__ comp,
    int* __restrict__ cursor, int2* __restrict__ packed2)
{
    int e4 = blockIdx.x * 256 + threadIdx.x;
    int4 d = reinterpret_cast<const int4*>(dst)[e4];
    int4 s = reinterpret_cast<const int4*>(src)[e4];
    int4 r = reinterpret_cast<const int4*>(rel)[e4];
    int dd[4] = { d.x, d.y, d.z, d.w };
    int ss[4] = { s.x, s.y, s.z, s.w };
    int rr[4] = { r.x, r.y, r.z, r.w };
    #pragma unroll
    for (int q = 0; q < 4; ++q) {
        float c0 = comp[rr[q] * 3 + 0];
        float c1 = comp[rr[q] * 3 + 1];
        float c2 = comp[rr[q] * 3 + 2];
        int w0 = ss[q] | ((int)f2bf(c0) << 16);
        int w1 = (int)f2bf(c1) | ((int)f2bf(c2) << 16);
        int pos = atomicAdd(&cursor[dd[q]], 1);
        packed2[pos] = make_int2(w0, w1);
    }
}

// ---------------------------------------------------------------------------
// FUSED aggregation + GEMM, K-SPLIT for occupancy. Block = 32 dst nodes,
// 256 threads (4 waves). Two rounds t=0,1; round t covers z columns
// {seg*256 + t*128 + i : i<128, seg<3} (global-k), i.e. a [32 x 384] z-tile.
// Phase 1 (per round): each wave aggregates 8 nodes; TWO edges per step
//   (half-wave each, 8 B/lane ushort4 gathers of half-rows), 12-shfl
//   cross-half reduction, dump bf16 into the swizzled LDS z-tile (24 KB).
// Phase 2 (per round): 12 k-steps, Wt slab 256x32 (16 KB) via
//   global_load_lds (kbase remapped), A-frags straight from the z-tile.
// LDS = 24+16 = 40 KB -> 4 blocks/CU, 16 waves/CU (2x R6's occupancy).
// ---------------------------------------------------------------------------
__global__ __launch_bounds__(256, 4) void fused_kernel(
    const unsigned short* __restrict__ hb,    // [N_NODES, 256] bf16
    const int2* __restrict__ packed2,         // sorted by dst
    const int* __restrict__ offsets,          // [N_NODES+1]
    const unsigned short* __restrict__ Wt,    // [256, 768] bf16
    const float* __restrict__ bias,           // [256]
    float* __restrict__ out)                  // [N_NODES, 256] f32
{
    __shared__ __align__(16) unsigned short Zs[ZROWS * 48 * 8];   // 24 KB
    __shared__ __align__(16) unsigned short Bs[256 * 4 * 8];      // 16 KB

    const int tid  = threadIdx.x;
    const int wave = tid >> 6, lane = tid & 63;
    const int quad = lane >> 4, l16 = lane & 15;
    const int half = lane >> 5;        // which edge of the pair
    const int f4   = lane & 31;        // feature-quad within the 128-block
    const int m0 = blockIdx.x * ZROWS;

    // B staging map (R6-proven): slot p -> col=p>>2, phys=p&3,
    // logical octet = phys ^ ((col>>1)&3).
    const unsigned short* gB[4];
    int lB[4];
    #pragma unroll
    for (int c = 0; c < 4; ++c) {
        int p = c * 256 + wave * 64 + lane;
        int col = p >> 2;
        int logical = (p & 3) ^ ((col >> 1) & 3);
        gB[c] = Wt + (size_t)col * K_DIM + logical * 8;
        lB[c] = (c * 256 + wave * 64) * 8;        // wave-uniform base (elems)
    }

    f32x4 acc[2][4] = {};

    for (int t = 0; t < 2; ++t) {
        __syncthreads();   // all waves done reading Zs (prev round)

        // ---------------- Phase 1: aggregate 8 nodes per wave -------------
        const unsigned short* hbase = hb + t * 128 + f4 * 4;
        for (int i = 0; i < 8; ++i) {
            const int m = wave * 8 + i;           // local z row
            const int node = m0 + m;
            const int start = offsets[node];
            const int end   = offsets[node + 1];

            float a[12] = {};
            for (int cb = start; cb < end; cb += 64) {
                int idx = cb + lane;
                int wx = 0, wy = 0;               // coef 0 for idx >= end
                if (idx < end) { int2 w = packed2[idx]; wx = w.x; wy = w.y; }
                int cnt = min(64, end - cb);
                for (int j = 0; j < cnt; j += 8) {
                    float c0[4], c1[4], c2[4];
                    ushort4 u[4];
                    #pragma unroll
                    for (int q = 0; q < 4; ++q) {
                        int e = j + 2 * q + half; // this half-wave's edge
                        int p0 = __shfl(wx, e);
                        int p1 = __shfl(wy, e);
                        int s = p0 & 0xFFFF;
                        c0[q] = bf2f((unsigned short)((unsigned)p0 >> 16));
                        c1[q] = bf2f((unsigned short)(p1 & 0xFFFF));
                        c2[q] = bf2f((unsigned short)((unsigned)p1 >> 16));
                        u[q] = *reinterpret_cast<const ushort4*>(
                            hbase + (size_t)s * IN_F);
                    }
                    #pragma unroll
                    for (int q = 0; q < 4; ++q) {
                        float v[4] = { bf2f(u[q].x), bf2f(u[q].y),
                                       bf2f(u[q].z), bf2f(u[q].w) };
                        #pragma unroll
                        for (int k = 0; k < 4; ++k) {
                            a[k]     += c0[q] * v[k];
                            a[4 + k] += c1[q] * v[k];
                            a[8 + k] += c2[q] * v[k];
                        }
                    }
                }
            }
            // Cross-half reduction (both halves hold the same features).
            #pragma unroll
            for (int k = 0; k < 12; ++k) a[k] += __shfl_xor(a[k], 32);
            if (half == 0) {
                // col = seg*128 + f4*4 -> oct = seg*16 + f4/2, half-slot f4&1
                #pragma unroll
                for (int seg = 0; seg < 3; ++seg) {
                    int oct  = seg * 16 + (f4 >> 1);
                    int phys = oct ^ (m & 7);
                    ushort4 o;
                    o.x = f2bf(a[seg * 4 + 0]); o.y = f2bf(a[seg * 4 + 1]);
                    o.z = f2bf(a[seg * 4 + 2]); o.w = f2bf(a[seg * 4 + 3]);
                    *reinterpret_cast<ushort4*>(
                        &Zs[(m * 48 + phys) * 8 + (f4 & 1) * 4]) = o;
                }
            }
        }
        __syncthreads();   // z-tile complete

        // ---------------- Phase 2: 12 k-steps of the GEMM -----------------
        for (int s = 0; s < 12; ++s) {
            if (s) __syncthreads();    // waves done reading Bs (prev step)
            int kbase = (s >> 2) * 256 + t * 128 + (s & 3) * 32;
            #pragma unroll
            for (int c = 0; c < 4; ++c)
                async_copy16(gB[c] + kbase, &Bs[lB[c]]);
            __syncthreads();           // copies drained (vmcnt(0) @ barrier)

            bf16x8 af[2], bfr[4];
            #pragma unroll
            for (int i = 0; i < 2; ++i) {
                int m = i * 16 + l16;
                int phys = (s * 4 + quad) ^ (m & 7);
                af[i] = *reinterpret_cast<const bf16x8*>(
                    &Zs[(m * 48 + phys) * 8]);
            }
            #pragma unroll
            for (int j = 0; j < 4; ++j) {
                int col = wave * 64 + j * 16 + l16;
                int physo = quad ^ ((col >> 1) & 3);
                bfr[j] = *reinterpret_cast<const bf16x8*>(
                    &Bs[(col * 4 + physo) * 8]);
            }
            #pragma unroll
            for (int i = 0; i < 2; ++i)
                #pragma unroll
                for (int j = 0; j < 4; ++j)
                    acc[i][j] = __builtin_amdgcn_mfma_f32_16x16x32_bf16(
                        af[i], bfr[j], acc[i][j], 0, 0, 0);
        }
    }

    // Epilogue: C/D layout col = l16, row = quad*4 + r. Fused bias + ReLU.
    #pragma unroll
    for (int j = 0; j < 4; ++j) {
        int col = wave * 64 + j * 16 + l16;
        float bv = bias[col];
        #pragma unroll
        for (int i = 0; i < 2; ++i) {
            int row_base = m0 + i * 16 + quad * 4;
            #pragma unroll
            for (int r = 0; r < 4; ++r)
                out[(size_t)(row_base + r) * OUT_F + col] =
                    fmaxf(acc[i][j][r] + bv, 0.f);
        }
    }
}

extern "C" void kernel_launch(void* const* d_in, const int* in_sizes, int n_in,
                              void* d_out, int out_size, void* d_ws, size_t ws_size,
                              hipStream_t stream) {
    const float* text  = (const float*)d_in[0];   // [64,512,256] f32
    const int*   src   = (const int*)d_in[1];     // [E]
    const int*   dst   = (const int*)d_in[2];     // [E]
    const int*   rel   = (const int*)d_in[3];     // [E]
    const float* bases = (const float*)d_in[4];   // [3,256,256] f32 = [768,256]
    const float* comp  = (const float*)d_in[5];   // [40,3] f32
    const float* bias  = (const float*)d_in[6];   // [256] f32
    float* out = (float*)d_out;

    // Workspace layout (~19.5 MB; all chunks 16B-aligned):
    //   hb      : N*256*2   = 16,777,216 B
    //   packed2 : E*8       =  2,097,152 B
    //   offsets : (N+4)*4   =    131,088 B
    //   counts  : N*4       =    131,072 B
    //   Wt      : 256*768*2 =    393,216 B
    char* p = (char*)d_ws;
    unsigned short* hb = (unsigned short*)p;      p += (size_t)N_NODES * IN_F * 2;
    int2* packed2 = (int2*)p;                     p += (size_t)N_EDGES * 8;
    int* offsets  = (int*)p;                      p += (size_t)(N_NODES + 4) * 4;
    int* counts   = (int*)p;                      p += (size_t)N_NODES * 4;
    unsigned short* Wt = (unsigned short*)p;

    prep_kernel<<<8512, 256, 0, stream>>>(text, bases, hb, Wt, counts);
    hist_kernel<<<N_EDGES / 1024, 256, 0, stream>>>(dst, counts);
    scan_kernel<<<1, 1024, 0, stream>>>(counts, offsets);
    scatter_kernel<<<N_EDGES / 1024, 256, 0, stream>>>(
        dst, src, rel, comp, counts, packed2);
    fused_kernel<<<N_NODES / ZROWS, 256, 0, stream>>>(
        hb, packed2, offsets, Wt, bias, out);
}

// Round 8
// 184.954 us; speedup vs baseline: 1.1463x; 1.1023x over previous
//
#include <hip/hip_runtime.h>
#include <cstdint>

// Problem constants (fixed by the reference: B=64,S=512,IN=OUT=256,R=40,NB=3,E=262144)
#define N_NODES 32768
#define IN_F    256
#define OUT_F   256
#define NBASES  3
#define N_EDGES 262144
#define K_DIM   (NBASES * IN_F)    // 768: GEMM reduction dim (b*256 + i)

typedef __attribute__((ext_vector_type(8))) short bf16x8;
typedef __attribute__((ext_vector_type(4))) float f32x4;

__device__ __forceinline__ unsigned short f2bf(float x) {
    union { float f; unsigned int u; } c; c.f = x;
    unsigned int u = c.u;
    u = (u + 0x7FFFu + ((u >> 16) & 1u)) >> 16;   // round-to-nearest-even
    return (unsigned short)u;
}
__device__ __forceinline__ float bf2f(unsigned short h) {
    union { unsigned int u; float f; } c; c.u = ((unsigned int)h) << 16;
    return c.f;
}

__device__ __forceinline__ void async_copy16(const void* g, void* l) {
    __builtin_amdgcn_global_load_lds(
        (const __attribute__((address_space(1))) unsigned int*)g,
        (__attribute__((address_space(3))) unsigned int*)l, 16, 0, 0);
}

// ---------------------------------------------------------------------------
// Prep (fused): blocks [0,8192) convert text f32 -> hb bf16; blocks
// [8192,8384) transpose bases -> Wt bf16; blocks [8384,8512) zero counts.
// ---------------------------------------------------------------------------
__global__ __launch_bounds__(256) void prep_kernel(
    const float* __restrict__ text,     // [N_NODES, 256] f32
    const float* __restrict__ bases,    // [768, 256] f32
    unsigned short* __restrict__ hb,    // [N_NODES, 256] bf16
    unsigned short* __restrict__ Wt,    // [256, 768] bf16
    int* __restrict__ counts)           // [N_NODES] -> zeroed
{
    const int tid = threadIdx.x;
    if (blockIdx.x < 8192) {
        int i = blockIdx.x * 256 + tid;            // float4 index
        float4 v = reinterpret_cast<const float4*>(text)[i];
        ushort4 o;
        o.x = f2bf(v.x); o.y = f2bf(v.y); o.z = f2bf(v.z); o.w = f2bf(v.w);
        reinterpret_cast<ushort4*>(hb)[i] = o;
    } else if (blockIdx.x < 8384) {
        int tb = blockIdx.x - 8192;                // [0,192)
        int kb = tb % 24, ob = tb / 24;            // 32-wide tiles
        __shared__ float tile[32][33];
        int c = tid & 31, r8 = tid >> 5;
        #pragma unroll
        for (int i = 0; i < 4; ++i) {
            int r = r8 + 8 * i;
            tile[r][c] = bases[(size_t)(kb * 32 + r) * OUT_F + ob * 32 + c];
        }
        __syncthreads();
        #pragma unroll
        for (int i = 0; i < 4; ++i) {
            int r = r8 + 8 * i;                    // output row within o-tile
            Wt[(size_t)(ob * 32 + r) * K_DIM + kb * 32 + c] = f2bf(tile[c][r]);
        }
    } else {
        int i = (blockIdx.x - 8384) * 256 + tid;   // [0, 32768)
        counts[i] = 0;
    }
}

// ---------------------------------------------------------------------------
// Counting sort of edges by dst: histogram -> scan -> scatter(packed int2)
// ---------------------------------------------------------------------------
__global__ __launch_bounds__(256) void hist_kernel(
    const int* __restrict__ dst, int* __restrict__ counts)
{
    int e4 = blockIdx.x * 256 + threadIdx.x;
    int4 d = reinterpret_cast<const int4*>(dst)[e4];
    atomicAdd(&counts[d.x], 1);
    atomicAdd(&counts[d.y], 1);
    atomicAdd(&counts[d.z], 1);
    atomicAdd(&counts[d.w], 1);
}

// Single block, 1024 threads, 32 counters each. Converts counts -> cursor
// in place and writes the exclusive-scan offsets.
__global__ __launch_bounds__(1024) void scan_kernel(
    int* __restrict__ counts,        // in: histogram; out: cursor (in place)
    int* __restrict__ offsets)       // [N_NODES+1]
{
    __shared__ int wsum[16];
    const int tid = threadIdx.x;
    const int wave = tid >> 6, lane = tid & 63;
    const int base = tid * 32;
    int local[32];
    int sum = 0;
    #pragma unroll
    for (int k8 = 0; k8 < 8; ++k8) {
        int4 v = reinterpret_cast<const int4*>(counts + base)[k8];
        local[k8 * 4 + 0] = v.x; local[k8 * 4 + 1] = v.y;
        local[k8 * 4 + 2] = v.z; local[k8 * 4 + 3] = v.w;
        sum += v.x + v.y + v.z + v.w;
    }
    int inc = sum;                            // wave-inclusive scan of sums
    #pragma unroll
    for (int off = 1; off < 64; off <<= 1) {
        int v = __shfl_up(inc, off);
        if (lane >= off) inc += v;
    }
    if (lane == 63) wsum[wave] = inc;
    __syncthreads();
    if (wave == 0 && lane < 16) {             // scan the 16 wave totals
        int v = wsum[lane];
        #pragma unroll
        for (int off = 1; off < 16; off <<= 1) {
            int u = __shfl_up(v, off);
            if (lane >= off) v += u;
        }
        wsum[lane] = v;
    }
    __syncthreads();
    int run = inc - sum + (wave ? wsum[wave - 1] : 0);   // exclusive prefix
    #pragma unroll
    for (int k = 0; k < 32; ++k) {
        offsets[base + k] = run;
        counts[base + k] = run;               // cursor
        run += local[k];
    }
    if (tid == 1023) offsets[N_NODES] = run;  // == N_EDGES
}

// Packs per-edge (src, bf16(comp[rel,0..2])) so agg needs no comp lookups
// and invalid lanes (coef=0) are harmless.
__global__ __launch_bounds__(256) void scatter_kernel(
    const int* __restrict__ dst, const int* __restrict__ src,
    const int* __restrict__ rel, const float* __restrict__ comp,
    int* __restrict__ cursor, int2* __restrict__ packed2)
{
    int e4 = blockIdx.x * 256 + threadIdx.x;
    int4 d = reinterpret_cast<const int4*>(dst)[e4];
    int4 s = reinterpret_cast<const int4*>(src)[e4];
    int4 r = reinterpret_cast<const int4*>(rel)[e4];
    int dd[4] = { d.x, d.y, d.z, d.w };
    int ss[4] = { s.x, s.y, s.z, s.w };
    int rr[4] = { r.x, r.y, r.z, r.w };
    #pragma unroll
    for (int q = 0; q < 4; ++q) {
        float c0 = comp[rr[q] * 3 + 0];
        float c1 = comp[rr[q] * 3 + 1];
        float c2 = comp[rr[q] * 3 + 2];
        int w0 = ss[q] | ((int)f2bf(c0) << 16);
        int w1 = (int)f2bf(c1) | ((int)f2bf(c2) << 16);
        int pos = atomicAdd(&cursor[dd[q]], 1);
        packed2[pos] = make_int2(w0, w1);
    }
}

// ---------------------------------------------------------------------------
// Aggregation in INPUT space: z[n, b, i] = sum_{e: dst=n} comp[rel_e,b]*h[src_e,i]
// One wave per dst node; lane owns 4 input features; 8-deep gather pipeline
// (mask-folded coefs, no tail branches). LDS-free -> max occupancy.
// ---------------------------------------------------------------------------
__global__ __launch_bounds__(256) void agg_kernel(
    const unsigned short* __restrict__ hb,    // [N_NODES, 256] bf16
    const int2* __restrict__ packed2,         // sorted by dst
    const int* __restrict__ offsets,          // [N_NODES+1]
    unsigned short* __restrict__ z)           // [N_NODES, 768] bf16
{
    const int node = blockIdx.x * 4 + (threadIdx.x >> 6);
    const int lane = threadIdx.x & 63;
    const int start = offsets[node];
    const int end   = offsets[node + 1];

    float a0[4] = {}, a1[4] = {}, a2[4] = {};
    const unsigned short* hp = hb + lane * 4;

    for (int cb = start; cb < end; cb += 64) {
        int idx = cb + lane;
        int wx = 0, wy = 0;                       // coef 0 for idx >= end
        if (idx < end) { int2 w = packed2[idx]; wx = w.x; wy = w.y; }
        int cnt = min(64, end - cb);
        for (int j = 0; j < cnt; j += 8) {
            float c0[8], c1[8], c2[8];
            ushort4 u[8];
            #pragma unroll
            for (int q = 0; q < 8; ++q) {         // 8 gathers in flight
                int p0 = __shfl(wx, j + q);
                int p1 = __shfl(wy, j + q);
                int s = p0 & 0xFFFF;
                float m = (j + q < cnt) ? 1.f : 0.f;
                c0[q] = m * bf2f((unsigned short)((unsigned)p0 >> 16));
                c1[q] = m * bf2f((unsigned short)(p1 & 0xFFFF));
                c2[q] = m * bf2f((unsigned short)((unsigned)p1 >> 16));
                u[q] = *reinterpret_cast<const ushort4*>(hp + (size_t)s * IN_F);
            }
            #pragma unroll
            for (int q = 0; q < 8; ++q) {
                float v[4] = { bf2f(u[q].x), bf2f(u[q].y),
                               bf2f(u[q].z), bf2f(u[q].w) };
                #pragma unroll
                for (int k = 0; k < 4; ++k) {
                    a0[k] += c0[q] * v[k];
                    a1[k] += c1[q] * v[k];
                    a2[k] += c2[q] * v[k];
                }
            }
        }
    }

    unsigned short* zp = z + (size_t)node * K_DIM + lane * 4;
    ushort4 o;
    o.x = f2bf(a0[0]); o.y = f2bf(a0[1]); o.z = f2bf(a0[2]); o.w = f2bf(a0[3]);
    *reinterpret_cast<ushort4*>(zp) = o;
    o.x = f2bf(a1[0]); o.y = f2bf(a1[1]); o.z = f2bf(a1[2]); o.w = f2bf(a1[3]);
    *reinterpret_cast<ushort4*>(zp + 256) = o;
    o.x = f2bf(a2[0]); o.y = f2bf(a2[1]); o.z = f2bf(a2[2]); o.w = f2bf(a2[3]);
    *reinterpret_cast<ushort4*>(zp + 512) = o;
}

// ---------------------------------------------------------------------------
// GEMM: out[m, o] = relu( sum_k z[m,k] * Wt[o,k] + bias[o] )
// M=32768, N=256, K=768. 128x128 tile, 4 waves (2x2), MFMA 16x16x32.
// DOUBLE-BUFFERED global_load_lds (one barrier/step; buf[s+1] copies overlap
// step s's ds_read+MFMA) into XOR-swizzled [row][k-octet] LDS (2-way max
// bank aliasing = free). 32 KB LDS.
// ---------------------------------------------------------------------------
__global__ __launch_bounds__(256) void gemm_kernel(
    const unsigned short* __restrict__ A,   // z  [32768, 768] bf16
    const unsigned short* __restrict__ Bt,  // Wt [256, 768] bf16
    const float* __restrict__ bias,         // [256]
    float* __restrict__ out)                // [32768, 256] f32
{
    __shared__ __align__(16) unsigned short As[2][128 * 32];   // 8 KB each
    __shared__ __align__(16) unsigned short Bs[2][128 * 32];

    const int tid  = threadIdx.x;
    const int wave = tid >> 6, lane = tid & 63;
    const int quad = lane >> 4, l16 = lane & 15;
    const int wm = (wave & 1) * 64, wn = (wave >> 1) * 64;
    const int m0 = blockIdx.x * 128, n0 = blockIdx.y * 128;

    f32x4 acc[4][4] = {};

    // Staging map: slot p <- logical (row = p>>2, oct = (p&3)^((row>>1)&3)).
    // A: 512 slots (2/thread); B: 512 slots (2/thread).
    const unsigned short *ga[2], *gb[2];
    int lab[2];
    #pragma unroll
    for (int c = 0; c < 2; ++c) {
        int p = c * 256 + wave * 64 + lane;
        int row = p >> 2;
        int oct = (p & 3) ^ ((row >> 1) & 3);
        ga[c] = A  + (size_t)(m0 + row) * K_DIM + oct * 8;
        gb[c] = Bt + (size_t)(n0 + row) * K_DIM + oct * 8;
        lab[c] = (c * 256 + wave * 64) * 8;       // wave-uniform base (elems)
    }

    // Prologue: stage k=0 into buffer 0.
    #pragma unroll
    for (int c = 0; c < 2; ++c) {
        async_copy16(ga[c], &As[0][lab[c]]);
        async_copy16(gb[c], &Bs[0][lab[c]]);
    }

    int cur = 0;
    for (int step = 0; step < K_DIM / 32; ++step) {
        __syncthreads();   // own-copies drained (vmcnt0) -> buf[cur] ready;
                           // all waves done reading buf[cur^1] from step-1
        int k1 = (step + 1) * 32;
        if (k1 < K_DIM) {  // prefetch next slab; overlaps ds_read+MFMA below
            #pragma unroll
            for (int c = 0; c < 2; ++c) {
                async_copy16(ga[c] + k1, &As[cur ^ 1][lab[c]]);
                async_copy16(gb[c] + k1, &Bs[cur ^ 1][lab[c]]);
            }
        }

        bf16x8 af[4], bfr[4];
        #pragma unroll
        for (int i = 0; i < 4; ++i) {
            int row = wm + i * 16 + l16;
            int oph = quad ^ ((row >> 1) & 3);
            af[i] = *reinterpret_cast<const bf16x8*>(&As[cur][(row * 4 + oph) * 8]);
            int nn   = wn + i * 16 + l16;
            int oph2 = quad ^ ((nn >> 1) & 3);
            bfr[i] = *reinterpret_cast<const bf16x8*>(&Bs[cur][(nn * 4 + oph2) * 8]);
        }
        #pragma unroll
        for (int i = 0; i < 4; ++i)
            #pragma unroll
            for (int j = 0; j < 4; ++j)
                acc[i][j] = __builtin_amdgcn_mfma_f32_16x16x32_bf16(
                    af[i], bfr[j], acc[i][j], 0, 0, 0);
        cur ^= 1;
    }

    // Epilogue: C/D layout col = l16, row = quad*4 + r. Fused bias + ReLU.
    #pragma unroll
    for (int j = 0; j < 4; ++j) {
        int col = n0 + wn + j * 16 + l16;
        float bv = bias[col];
        #pragma unroll
        for (int i = 0; i < 4; ++i) {
            int row_base = m0 + wm + i * 16 + quad * 4;
            #pragma unroll
            for (int r = 0; r < 4; ++r)
                out[(size_t)(row_base + r) * OUT_F + col] =
                    fmaxf(acc[i][j][r] + bv, 0.f);
        }
    }
}

extern "C" void kernel_launch(void* const* d_in, const int* in_sizes, int n_in,
                              void* d_out, int out_size, void* d_ws, size_t ws_size,
                              hipStream_t stream) {
    const float* text  = (const float*)d_in[0];   // [64,512,256] f32
    const int*   src   = (const int*)d_in[1];     // [E]
    const int*   dst   = (const int*)d_in[2];     // [E]
    const int*   rel   = (const int*)d_in[3];     // [E]
    const float* bases = (const float*)d_in[4];   // [3,256,256] f32 = [768,256]
    const float* comp  = (const float*)d_in[5];   // [40,3] f32
    const float* bias  = (const float*)d_in[6];   // [256] f32
    float* out = (float*)d_out;

    // Workspace layout (~70 MB; all chunks 16B-aligned):
    //   z       : N*768*2   = 50,331,648 B
    //   hb      : N*256*2   = 16,777,216 B
    //   packed2 : E*8       =  2,097,152 B
    //   offsets : (N+4)*4   =    131,088 B
    //   counts  : N*4       =    131,072 B
    //   Wt      : 256*768*2 =    393,216 B
    char* p = (char*)d_ws;
    unsigned short* z  = (unsigned short*)p;      p += (size_t)N_NODES * K_DIM * 2;
    unsigned short* hb = (unsigned short*)p;      p += (size_t)N_NODES * IN_F * 2;
    int2* packed2 = (int2*)p;                     p += (size_t)N_EDGES * 8;
    int* offsets  = (int*)p;                      p += (size_t)(N_NODES + 4) * 4;
    int* counts   = (int*)p;                      p += (size_t)N_NODES * 4;
    unsigned short* Wt = (unsigned short*)p;

    prep_kernel<<<8512, 256, 0, stream>>>(text, bases, hb, Wt, counts);
    hist_kernel<<<N_EDGES / 1024, 256, 0, stream>>>(dst, counts);
    scan_kernel<<<1, 1024, 0, stream>>>(counts, offsets);
    scatter_kernel<<<N_EDGES / 1024, 256, 0, stream>>>(
        dst, src, rel, comp, counts, packed2);
    agg_kernel<<<N_NODES / 4, 256, 0, stream>>>(hb, packed2, offsets, z);
    gemm_kernel<<<dim3(N_NODES / 128, OUT_F / 128), 256, 0, stream>>>(
        z, Wt, bias, out);
}

// Round 9
// 176.548 us; speedup vs baseline: 1.2009x; 1.0476x over previous
//
#include <hip/hip_runtime.h>
#include <cstdint>

// Problem constants (fixed by the reference: B=64,S=512,IN=OUT=256,R=40,NB=3,E=262144)
#define N_NODES 32768
#define IN_F    256
#define OUT_F   256
#define NBASES  3
#define N_EDGES 262144
#define K_DIM   (NBASES * IN_F)    // 768: GEMM reduction dim (b*256 + i)

typedef __attribute__((ext_vector_type(8))) short bf16x8;
typedef __attribute__((ext_vector_type(4))) float f32x4;

__device__ __forceinline__ unsigned short f2bf(float x) {
    union { float f; unsigned int u; } c; c.f = x;
    unsigned int u = c.u;
    u = (u + 0x7FFFu + ((u >> 16) & 1u)) >> 16;   // round-to-nearest-even
    return (unsigned short)u;
}
__device__ __forceinline__ float bf2f(unsigned short h) {
    union { unsigned int u; float f; } c; c.u = ((unsigned int)h) << 16;
    return c.f;
}

__device__ __forceinline__ void async_copy16(const void* g, void* l) {
    __builtin_amdgcn_global_load_lds(
        (const __attribute__((address_space(1))) unsigned int*)g,
        (__attribute__((address_space(3))) unsigned int*)l, 16, 0, 0);
}

// ---------------------------------------------------------------------------
// Prep (fused): blocks [0,8192) convert text f32 -> hb bf16; blocks
// [8192,8384) transpose bases -> Wt bf16; blocks [8384,8512) zero counts.
// ---------------------------------------------------------------------------
__global__ __launch_bounds__(256) void prep_kernel(
    const float* __restrict__ text,     // [N_NODES, 256] f32
    const float* __restrict__ bases,    // [768, 256] f32
    unsigned short* __restrict__ hb,    // [N_NODES, 256] bf16
    unsigned short* __restrict__ Wt,    // [256, 768] bf16
    int* __restrict__ counts)           // [N_NODES] -> zeroed
{
    const int tid = threadIdx.x;
    if (blockIdx.x < 8192) {
        int i = blockIdx.x * 256 + tid;            // float4 index
        float4 v = reinterpret_cast<const float4*>(text)[i];
        ushort4 o;
        o.x = f2bf(v.x); o.y = f2bf(v.y); o.z = f2bf(v.z); o.w = f2bf(v.w);
        reinterpret_cast<ushort4*>(hb)[i] = o;
    } else if (blockIdx.x < 8384) {
        int tb = blockIdx.x - 8192;                // [0,192)
        int kb = tb % 24, ob = tb / 24;            // 32-wide tiles
        __shared__ float tile[32][33];
        int c = tid & 31, r8 = tid >> 5;
        #pragma unroll
        for (int i = 0; i < 4; ++i) {
            int r = r8 + 8 * i;
            tile[r][c] = bases[(size_t)(kb * 32 + r) * OUT_F + ob * 32 + c];
        }
        __syncthreads();
        #pragma unroll
        for (int i = 0; i < 4; ++i) {
            int r = r8 + 8 * i;                    // output row within o-tile
            Wt[(size_t)(ob * 32 + r) * K_DIM + kb * 32 + c] = f2bf(tile[c][r]);
        }
    } else {
        int i = (blockIdx.x - 8384) * 256 + tid;   // [0, 32768)
        counts[i] = 0;
    }
}

// ---------------------------------------------------------------------------
// Counting sort of edges by dst: histogram -> scan -> scatter(packed int2)
// ---------------------------------------------------------------------------
__global__ __launch_bounds__(256) void hist_kernel(
    const int* __restrict__ dst, int* __restrict__ counts)
{
    int e4 = blockIdx.x * 256 + threadIdx.x;
    int4 d = reinterpret_cast<const int4*>(dst)[e4];
    atomicAdd(&counts[d.x], 1);
    atomicAdd(&counts[d.y], 1);
    atomicAdd(&counts[d.z], 1);
    atomicAdd(&counts[d.w], 1);
}

// Single block, 1024 threads, 32 counters each. Converts counts -> cursor
// in place and writes the exclusive-scan offsets.
__global__ __launch_bounds__(1024) void scan_kernel(
    int* __restrict__ counts,        // in: histogram; out: cursor (in place)
    int* __restrict__ offsets)       // [N_NODES+1]
{
    __shared__ int wsum[16];
    const int tid = threadIdx.x;
    const int wave = tid >> 6, lane = tid & 63;
    const int base = tid * 32;
    int local[32];
    int sum = 0;
    #pragma unroll
    for (int k8 = 0; k8 < 8; ++k8) {
        int4 v = reinterpret_cast<const int4*>(counts + base)[k8];
        local[k8 * 4 + 0] = v.x; local[k8 * 4 + 1] = v.y;
        local[k8 * 4 + 2] = v.z; local[k8 * 4 + 3] = v.w;
        sum += v.x + v.y + v.z + v.w;
    }
    int inc = sum;                            // wave-inclusive scan of sums
    #pragma unroll
    for (int off = 1; off < 64; off <<= 1) {
        int v = __shfl_up(inc, off);
        if (lane >= off) inc += v;
    }
    if (lane == 63) wsum[wave] = inc;
    __syncthreads();
    if (wave == 0 && lane < 16) {             // scan the 16 wave totals
        int v = wsum[lane];
        #pragma unroll
        for (int off = 1; off < 16; off <<= 1) {
            int u = __shfl_up(v, off);
            if (lane >= off) v += u;
        }
        wsum[lane] = v;
    }
    __syncthreads();
    int run = inc - sum + (wave ? wsum[wave - 1] : 0);   // exclusive prefix
    #pragma unroll
    for (int k = 0; k < 32; ++k) {
        offsets[base + k] = run;
        counts[base + k] = run;               // cursor
        run += local[k];
    }
    if (tid == 1023) offsets[N_NODES] = run;  // == N_EDGES
}

// Packs per-edge (src, bf16(comp[rel,0..2])) so agg needs no comp lookups
// and invalid lanes (coef=0) are harmless.
__global__ __launch_bounds__(256) void scatter_kernel(
    const int* __restrict__ dst, const int* __restrict__ src,
    const int* __restrict__ rel, const float* __restrict__ comp,
    int* __restrict__ cursor, int2* __restrict__ packed2)
{
    int e4 = blockIdx.x * 256 + threadIdx.x;
    int4 d = reinterpret_cast<const int4*>(dst)[e4];
    int4 s = reinterpret_cast<const int4*>(src)[e4];
    int4 r = reinterpret_cast<const int4*>(rel)[e4];
    int dd[4] = { d.x, d.y, d.z, d.w };
    int ss[4] = { s.x, s.y, s.z, s.w };
    int rr[4] = { r.x, r.y, r.z, r.w };
    #pragma unroll
    for (int q = 0; q < 4; ++q) {
        float c0 = comp[rr[q] * 3 + 0];
        float c1 = comp[rr[q] * 3 + 1];
        float c2 = comp[rr[q] * 3 + 2];
        int w0 = ss[q] | ((int)f2bf(c0) << 16);
        int w1 = (int)f2bf(c1) | ((int)f2bf(c2) << 16);
        int pos = atomicAdd(&cursor[dd[q]], 1);
        packed2[pos] = make_int2(w0, w1);
    }
}

// ---------------------------------------------------------------------------
// Aggregation in INPUT space: z[n, b, i] = sum_{e: dst=n} comp[rel_e,b]*h[src_e,i]
// One wave per dst node; lane owns 4 input features; 8-deep gather pipeline
// (mask-folded coefs, no tail branches). LDS-free -> max occupancy.
// ---------------------------------------------------------------------------
__global__ __launch_bounds__(256) void agg_kernel(
    const unsigned short* __restrict__ hb,    // [N_NODES, 256] bf16
    const int2* __restrict__ packed2,         // sorted by dst
    const int* __restrict__ offsets,          // [N_NODES+1]
    unsigned short* __restrict__ z)           // [N_NODES, 768] bf16
{
    const int node = blockIdx.x * 4 + (threadIdx.x >> 6);
    const int lane = threadIdx.x & 63;
    const int start = offsets[node];
    const int end   = offsets[node + 1];

    float a0[4] = {}, a1[4] = {}, a2[4] = {};
    const unsigned short* hp = hb + lane * 4;

    for (int cb = start; cb < end; cb += 64) {
        int idx = cb + lane;
        int wx = 0, wy = 0;                       // coef 0 for idx >= end
        if (idx < end) { int2 w = packed2[idx]; wx = w.x; wy = w.y; }
        int cnt = min(64, end - cb);
        for (int j = 0; j < cnt; j += 8) {
            float c0[8], c1[8], c2[8];
            ushort4 u[8];
            #pragma unroll
            for (int q = 0; q < 8; ++q) {         // 8 gathers in flight
                int p0 = __shfl(wx, j + q);
                int p1 = __shfl(wy, j + q);
                int s = p0 & 0xFFFF;
                float m = (j + q < cnt) ? 1.f : 0.f;
                c0[q] = m * bf2f((unsigned short)((unsigned)p0 >> 16));
                c1[q] = m * bf2f((unsigned short)(p1 & 0xFFFF));
                c2[q] = m * bf2f((unsigned short)((unsigned)p1 >> 16));
                u[q] = *reinterpret_cast<const ushort4*>(hp + (size_t)s * IN_F);
            }
            #pragma unroll
            for (int q = 0; q < 8; ++q) {
                float v[4] = { bf2f(u[q].x), bf2f(u[q].y),
                               bf2f(u[q].z), bf2f(u[q].w) };
                #pragma unroll
                for (int k = 0; k < 4; ++k) {
                    a0[k] += c0[q] * v[k];
                    a1[k] += c1[q] * v[k];
                    a2[k] += c2[q] * v[k];
                }
            }
        }
    }

    unsigned short* zp = z + (size_t)node * K_DIM + lane * 4;
    ushort4 o;
    o.x = f2bf(a0[0]); o.y = f2bf(a0[1]); o.z = f2bf(a0[2]); o.w = f2bf(a0[3]);
    *reinterpret_cast<ushort4*>(zp) = o;
    o.x = f2bf(a1[0]); o.y = f2bf(a1[1]); o.z = f2bf(a1[2]); o.w = f2bf(a1[3]);
    *reinterpret_cast<ushort4*>(zp + 256) = o;
    o.x = f2bf(a2[0]); o.y = f2bf(a2[1]); o.z = f2bf(a2[2]); o.w = f2bf(a2[3]);
    *reinterpret_cast<ushort4*>(zp + 512) = o;
}

// ---------------------------------------------------------------------------
// GEMM: out[m, o] = relu( sum_k z[m,k] * Wt[o,k] + bias[o] )
// M=32768, N=256, K=768. 128x128 tile, 4 waves (2x2), MFMA 16x16x32.
// BK=64: 32 MFMAs per barrier (AITER ratio), 12 barriers total.
// DOUBLE-BUFFERED global_load_lds into XOR-swizzled [row][k-octet] LDS
// (8 octets/row, phys = oct ^ ((row>>1)&7): fragment-read banks = phys*4,
// 8 runs x 2 lanes = 2-way aliasing = free). 64 KB LDS; grid is 512 blocks
// = 2/CU, so the LDS increase costs no occupancy (m132 caveat inapplicable).
// ---------------------------------------------------------------------------
__global__ __launch_bounds__(256) void gemm_kernel(
    const unsigned short* __restrict__ A,   // z  [32768, 768] bf16
    const unsigned short* __restrict__ Bt,  // Wt [256, 768] bf16
    const float* __restrict__ bias,         // [256]
    float* __restrict__ out)                // [32768, 256] f32
{
    __shared__ __align__(16) unsigned short As[2][128 * 64];   // 16 KB each
    __shared__ __align__(16) unsigned short Bs[2][128 * 64];

    const int tid  = threadIdx.x;
    const int wave = tid >> 6, lane = tid & 63;
    const int quad = lane >> 4, l16 = lane & 15;
    const int wm = (wave & 1) * 64, wn = (wave >> 1) * 64;
    const int m0 = blockIdx.x * 128, n0 = blockIdx.y * 128;

    f32x4 acc[4][4] = {};

    // Staging map: 1024 16-B slots per matrix per step; slot p <- logical
    // (row = p>>3, oct = (p&7)^((row>>1)&7)). 4 copies/thread per matrix.
    const unsigned short *ga[4], *gb[4];
    int lab[4];
    #pragma unroll
    for (int c = 0; c < 4; ++c) {
        int p = c * 256 + wave * 64 + lane;
        int row = p >> 3;
        int oct = (p & 7) ^ ((row >> 1) & 7);
        ga[c] = A  + (size_t)(m0 + row) * K_DIM + oct * 8;
        gb[c] = Bt + (size_t)(n0 + row) * K_DIM + oct * 8;
        lab[c] = (c * 256 + wave * 64) * 8;       // wave-uniform base (elems)
    }

    // Prologue: stage k=0 into buffer 0.
    #pragma unroll
    for (int c = 0; c < 4; ++c) {
        async_copy16(ga[c], &As[0][lab[c]]);
        async_copy16(gb[c], &Bs[0][lab[c]]);
    }

    int cur = 0;
    for (int step = 0; step < K_DIM / 64; ++step) {
        __syncthreads();   // own-copies drained (vmcnt0) -> buf[cur] ready;
                           // all waves done reading buf[cur^1] from step-1
        int k1 = (step + 1) * 64;
        if (k1 < K_DIM) {  // prefetch next slab; overlaps ds_read+MFMA below
            #pragma unroll
            for (int c = 0; c < 4; ++c) {
                async_copy16(ga[c] + k1, &As[cur ^ 1][lab[c]]);
                async_copy16(gb[c] + k1, &Bs[cur ^ 1][lab[c]]);
            }
        }

        #pragma unroll
        for (int s2 = 0; s2 < 2; ++s2) {          // two 32-k sub-steps
            bf16x8 af[4], bfr[4];
            #pragma unroll
            for (int i = 0; i < 4; ++i) {
                int row = wm + i * 16 + l16;
                int oph = (s2 * 4 + quad) ^ ((row >> 1) & 7);
                af[i] = *reinterpret_cast<const bf16x8*>(
                    &As[cur][(row * 8 + oph) * 8]);
                int nn   = wn + i * 16 + l16;
                int oph2 = (s2 * 4 + quad) ^ ((nn >> 1) & 7);
                bfr[i] = *reinterpret_cast<const bf16x8*>(
                    &Bs[cur][(nn * 8 + oph2) * 8]);
            }
            #pragma unroll
            for (int i = 0; i < 4; ++i)
                #pragma unroll
                for (int j = 0; j < 4; ++j)
                    acc[i][j] = __builtin_amdgcn_mfma_f32_16x16x32_bf16(
                        af[i], bfr[j], acc[i][j], 0, 0, 0);
        }
        cur ^= 1;
    }

    // Epilogue: C/D layout col = l16, row = quad*4 + r. Fused bias + ReLU.
    #pragma unroll
    for (int j = 0; j < 4; ++j) {
        int col = n0 + wn + j * 16 + l16;
        float bv = bias[col];
        #pragma unroll
        for (int i = 0; i < 4; ++i) {
            int row_base = m0 + wm + i * 16 + quad * 4;
            #pragma unroll
            for (int r = 0; r < 4; ++r)
                out[(size_t)(row_base + r) * OUT_F + col] =
                    fmaxf(acc[i][j][r] + bv, 0.f);
        }
    }
}

extern "C" void kernel_launch(void* const* d_in, const int* in_sizes, int n_in,
                              void* d_out, int out_size, void* d_ws, size_t ws_size,
                              hipStream_t stream) {
    const float* text  = (const float*)d_in[0];   // [64,512,256] f32
    const int*   src   = (const int*)d_in[1];     // [E]
    const int*   dst   = (const int*)d_in[2];     // [E]
    const int*   rel   = (const int*)d_in[3];     // [E]
    const float* bases = (const float*)d_in[4];   // [3,256,256] f32 = [768,256]
    const float* comp  = (const float*)d_in[5];   // [40,3] f32
    const float* bias  = (const float*)d_in[6];   // [256] f32
    float* out = (float*)d_out;

    // Workspace layout (~70 MB; all chunks 16B-aligned):
    //   z       : N*768*2   = 50,331,648 B
    //   hb      : N*256*2   = 16,777,216 B
    //   packed2 : E*8       =  2,097,152 B
    //   offsets : (N+4)*4   =    131,088 B
    //   counts  : N*4       =    131,072 B
    //   Wt      : 256*768*2 =    393,216 B
    char* p = (char*)d_ws;
    unsigned short* z  = (unsigned short*)p;      p += (size_t)N_NODES * K_DIM * 2;
    unsigned short* hb = (unsigned short*)p;      p += (size_t)N_NODES * IN_F * 2;
    int2* packed2 = (int2*)p;                     p += (size_t)N_EDGES * 8;
    int* offsets  = (int*)p;                      p += (size_t)(N_NODES + 4) * 4;
    int* counts   = (int*)p;                      p += (size_t)N_NODES * 4;
    unsigned short* Wt = (unsigned short*)p;

    prep_kernel<<<8512, 256, 0, stream>>>(text, bases, hb, Wt, counts);
    hist_kernel<<<N_EDGES / 1024, 256, 0, stream>>>(dst, counts);
    scan_kernel<<<1, 1024, 0, stream>>>(counts, offsets);
    scatter_kernel<<<N_EDGES / 1024, 256, 0, stream>>>(
        dst, src, rel, comp, counts, packed2);
    agg_kernel<<<N_NODES / 4, 256, 0, stream>>>(hb, packed2, offsets, z);
    gemm_kernel<<<dim3(N_NODES / 128, OUT_F / 128), 256, 0, stream>>>(
        z, Wt, bias, out);
}